// Round 17
// baseline (162.385 us; speedup 1.0000x reference)
//
#include <hip/hip_runtime.h>
#include <hip/hip_bf16.h>

// Problem constants
#define B_    2
#define QN    100
#define NP    6
#define WS2   49
#define CC    256
#define NHH   8
#define HDD   32
#define NWIN  600            // Q*Np windows per batch

// ws layout (bytes): xT fp32 (+1KB zero page) | wbp bf16 | wpT fp32 | o16 bf16
#define XT_BYTES   (8388608 + 1024)
#define ZABS       2097152                  // element index of the zero page in xT
#define WB_BYTES   393216
#define WPT_BYTES  262144

#define SPB_LD 264   // bf16 sp row stride (shorts); 49 rows only (A-reads clamp to 48)

// per-wave LDS region: 49 rows x 64 shorts (128B), XOR-swizzled slots.
// Holds Q|K during QK^T, then P, then Ow (fp32, 32 floats/row) — all overlays,
// same-wave ds program order. V never touches LDS (shfl+bit_cast repack).
// r6/r11-hardware-verified algebra; spills there were f2bf register pressure
// (fixed r16: intrinsic f2bf freed ~40 VGPR on the r8 base).
#define RG_SHORTS (WS2 * 64)     // 3136 shorts = 6272 B per wave

typedef __attribute__((ext_vector_type(8))) short bf16x8;
typedef __attribute__((ext_vector_type(4))) float f32x4;
typedef __attribute__((ext_vector_type(4))) unsigned int u32x4;

// RNE f32->bf16 via the HIP intrinsic (r16-proven: compiler emits native convert;
// hand-rolled bit-twiddle cost ~40 VGPR + 3 VALU/call). Same numerics.
__device__ __forceinline__ unsigned short f2bf(float f) {
  return __builtin_bit_cast(unsigned short, __float2bfloat16(f));
}
__device__ __forceinline__ float bf2f(unsigned short u) {
  union { unsigned int i; float f; } v; v.i = ((unsigned int)u) << 16; return v.f;
}
__device__ __forceinline__ unsigned int pk2(float a, float b) {
  return (unsigned int)f2bf(a) | ((unsigned int)f2bf(b) << 16);
}

// ---------- K0: x-transpose float4 64x64 (0..511) + wbp pack (512..607)
//             + zero page (608) + w_proj transpose (609..672) ----------
__global__ void k0_prep(const float* __restrict__ x, float* __restrict__ xT,
                        const float* __restrict__ w_qkv, unsigned short* __restrict__ wbp,
                        const float* __restrict__ w_proj, float* __restrict__ wpT) {
  __shared__ float tile[64][65];
  const int gb = blockIdx.x;
  if (gb < 512) {
    // 64x64 tile, float4 on BOTH global sides (16B/lane)
    int b   = gb >> 8;
    int rem = gb & 255;              // 64 hw-tiles x 4 c-tiles
    int hw0 = (rem & 63) * 64;
    int c0  = (rem >> 6) * 64;
    int tx = threadIdx.x & 15, ty = threadIdx.x >> 4;   // 16x16
    const float* src = x + (size_t)b * CC * 4096;
    float* dst = xT + (size_t)b * 4096 * CC;
    #pragma unroll
    for (int i = 0; i < 4; i++) {
      int cl = ty + i * 16;
      float4 v = *(const float4*)(src + (size_t)(c0 + cl) * 4096 + hw0 + tx * 4);
      tile[tx * 4 + 0][cl] = v.x;
      tile[tx * 4 + 1][cl] = v.y;
      tile[tx * 4 + 2][cl] = v.z;
      tile[tx * 4 + 3][cl] = v.w;
    }
    __syncthreads();
    #pragma unroll
    for (int i = 0; i < 4; i++) {
      int hl = ty + i * 16;
      float4 v;
      v.x = tile[hl][tx * 4 + 0];
      v.y = tile[hl][tx * 4 + 1];
      v.z = tile[hl][tx * 4 + 2];
      v.w = tile[hl][tx * 4 + 3];
      *(float4*)(dst + (size_t)(hw0 + hl) * 256 + c0 + tx * 4) = v;
    }
  } else if (gb < 608) {
    // wbp[((nt*8+ks)*64+lane)*8+i] = bf16(w_qkv[nt*16+(lane&15)][ks*32+(lane>>4)*8+i])
    int g = (gb - 512) * 256 + threadIdx.x;       // 0..24575
    int lane = g & 63;
    int ks = (g >> 6) & 7;
    int nt = g >> 9;
    int n  = nt * 16 + (lane & 15);
    int k0 = ks * 32 + (lane >> 4) * 8;
    const float* src = w_qkv + (size_t)n * CC + k0;
    float4 lo = *(const float4*)(src);
    float4 hi = *(const float4*)(src + 4);
    unsigned short o[8] = { f2bf(lo.x), f2bf(lo.y), f2bf(lo.z), f2bf(lo.w),
                            f2bf(hi.x), f2bf(hi.y), f2bf(hi.z), f2bf(hi.w) };
    *(uint4*)(wbp + (size_t)g * 8) = *(uint4*)o;
  } else if (gb == 608) {
    xT[ZABS + threadIdx.x] = 0.0f;   // zero page for invalid bilinear corners
  } else {
    // wpT[c][j] = w_proj[j][c]
    int t = gb - 609;                // 0..63
    int r0 = (t >> 3) * 32;          // j tile
    int c0 = (t & 7) * 32;           // c tile
    int tx = threadIdx.x & 31, ty = threadIdx.x >> 5;
    #pragma unroll
    for (int i = ty; i < 32; i += 8)
      tile[i][tx] = w_proj[(size_t)(r0 + i) * CC + c0 + tx];
    __syncthreads();
    #pragma unroll
    for (int i = ty; i < 32; i += 8)
      wpT[(size_t)(c0 + i) * CC + r0 + tx] = tile[tx][i];
  }
}

// ---------- K12: fused sample + QKV GEMM + attention, LDS-diet single-head passes ----------
// LDS = spb 25872 + 4x6272 = 50960 B -> 3 blocks/CU if VGPR <= ~170 (intrinsic f2bf
// freed ~40 VGPR; diet machinery costs ~25-35 -> expect ~115-125, no spill).
__launch_bounds__(256, 2)
__global__ void k12_fused(const float* __restrict__ xT,
                          const float* __restrict__ polys,
                          const unsigned short* __restrict__ wbp,
                          const float* __restrict__ b_qkv,
                          unsigned short* __restrict__ o16) {
  __shared__ __align__(16) unsigned short spb[WS2 * SPB_LD];      // 25872 B
  __shared__ __align__(16) unsigned short wreg[4 * RG_SHORTS];    // 25088 B
  // co tables alias wave 0's region (dead until GEMM stores; co dead after Phase B)
  int*   co_off = (int*)wreg;                   // [49][4] ints, 784 B
  float* co_w   = (float*)wreg + 196;           // [49][4] floats, next 784 B
  const int tid = threadIdx.x;
  // XCD-chunked bijective swizzle (600 = 8*75)
  const int m = (blockIdx.x & 7) * 75 + (blockIdx.x >> 3);
  const int b = blockIdx.y;
  const int lane = tid & 63;
  const int wv = tid >> 6;
  const int lm = lane & 15;
  const int lg = lane >> 4;
  unsigned short* myreg = wreg + wv * RG_SHORTS;

  // Phase A: per-row offsets + weights (grid scramble: n = m*49+r)
  if (tid < WS2) {
    int n = m * WS2 + tid;
    int q = n / (WS2 * NP);
    int p = (n / NP) % WS2;
    int a = n % NP;
    const float* pc = polys + (size_t)(b * QN + q) * 12;
    float al = (float)a * 0.2f;
    float py = pc[0];
    float px = pc[6];
    #pragma unroll
    for (int i = 1; i < 6; i++) { py = py * al + pc[i]; px = px * al + pc[6 + i]; }
    py = 2.0f * py - 1.0f;
    px = 2.0f * px - 1.0f;
    float gy = py + (2.0f * (-4.0f + (float)(p / 7) * (7.0f / 6.0f))) * (1.0f / 64.0f);
    float gx = px + (2.0f * (-4.0f + (float)(p % 7) * (7.0f / 6.0f))) * (1.0f / 64.0f);
    // NOTE the reference swap: fx from grid_y, fy from grid_x
    float fx = (gy + 1.0f) * 0.5f * 63.0f;
    float fy = (gx + 1.0f) * 0.5f * 63.0f;
    float x0 = floorf(fx), y0 = floorf(fy);
    float wx = fx - x0, wy = fy - y0;
    float x1 = x0 + 1.0f, y1 = y0 + 1.0f;
    int xi0 = (int)fminf(fmaxf(x0, 0.0f), 63.0f);
    int yi0 = (int)fminf(fmaxf(y0, 0.0f), 63.0f);
    int xi1 = (int)fminf(fmaxf(x1, 0.0f), 63.0f);
    int yi1 = (int)fminf(fmaxf(y1, 0.0f), 63.0f);
    bool vx0 = (x0 >= 0.0f) && (x0 <= 63.0f);
    bool vx1 = (x1 >= 0.0f) && (x1 <= 63.0f);
    bool vy0 = (y0 >= 0.0f) && (y0 <= 63.0f);
    bool vy1 = (y1 >= 0.0f) && (y1 <= 63.0f);
    const int bb = b * 4096;
    co_off[tid * 4 + 0] = (vx0 && vy0) ? (bb + yi0 * 64 + xi0) * CC : ZABS;
    co_off[tid * 4 + 1] = (vx1 && vy0) ? (bb + yi0 * 64 + xi1) * CC : ZABS;
    co_off[tid * 4 + 2] = (vx0 && vy1) ? (bb + yi1 * 64 + xi0) * CC : ZABS;
    co_off[tid * 4 + 3] = (vx1 && vy1) ? (bb + yi1 * 64 + xi1) * CC : ZABS;
    co_w[tid * 4 + 0] = (1.0f - wy) * (1.0f - wx);
    co_w[tid * 4 + 1] = (1.0f - wy) * wx;
    co_w[tid * 4 + 2] = wy * (1.0f - wx);
    co_w[tid * 4 + 3] = wy * wx;
  }
  __syncthreads();

  // Phase B: bilinear sampling, thread = channel, batch-8 rows (32 loads in flight)
  for (int bi = 0; bi < 6; bi++) {
    const int rbase = bi * 8;
    float vv[8][4];
    #pragma unroll
    for (int k = 0; k < 8; k++) {
      int r = rbase + k;
      int4 off = *(const int4*)&co_off[r * 4];
      vv[k][0] = xT[off.x + tid];
      vv[k][1] = xT[off.y + tid];
      vv[k][2] = xT[off.z + tid];
      vv[k][3] = xT[off.w + tid];
    }
    #pragma unroll
    for (int k = 0; k < 8; k++) {
      int r = rbase + k;
      float4 w = *(const float4*)&co_w[r * 4];
      float s = vv[k][0] * w.x + vv[k][1] * w.y + vv[k][2] * w.z + vv[k][3] * w.w;
      spb[r * SPB_LD + tid] = f2bf(s);
    }
  }
  {  // tail row 48
    int4 off = *(const int4*)&co_off[48 * 4];
    float4 w = *(const float4*)&co_w[48 * 4];
    float s = xT[off.x + tid] * w.x + xT[off.y + tid] * w.y
            + xT[off.z + tid] * w.z + xT[off.w + tid] * w.w;
    spb[48 * SPB_LD + tid] = f2bf(s);
  }
  __syncthreads();

  // clamped A-row bases (rows >=49 duplicate row 48; results provably masked:
  // Q/K/P stores guarded rr<49, S cols 49-63 forced -1e30, P rows >=49 never read)
  int rowb[4];
  #pragma unroll
  for (int mt = 0; mt < 4; mt++) {
    int r = mt * 16 + lm; if (r > 48) r = 48;
    rowb[mt] = r * SPB_LD;
  }

  unsigned short* obase = o16 + (size_t)(b * NWIN + m) * 392 * 32;
  const float scale = 0.17677669529663687f;  // 1/sqrt(32)

  // Two single-head passes: h = 2*wv + hp
  for (int hp = 0; hp < 2; hp++) {
    const int h = 2 * wv + hp;
    unsigned int vpk[4][2][2];   // packed bf16 V accumulators [mt][j4][word]

    // GEMM: jc=0 -> Q (region cols 0..31), jc=1 -> K (32..63), jc=2 -> V (regs)
    for (int jc = 0; jc < 3; jc++) {
      const int nt0 = jc * 16 + 2 * h;
      f32x4 acc[4][2];
      #pragma unroll
      for (int j4 = 0; j4 < 2; j4++) {
        float bias = b_qkv[(nt0 + j4) * 16 + lm];
        #pragma unroll
        for (int mt = 0; mt < 4; mt++) acc[mt][j4] = (f32x4){bias, bias, bias, bias};
      }
      // 2-deep register prefetch for B fragments (r8-proven)
      bf16x8 bnx[2][2];   // [ks parity][j4]
      #pragma unroll
      for (int j4 = 0; j4 < 2; j4++) {
        bnx[0][j4] = *(const bf16x8*)(wbp + (size_t)(((nt0 + j4) * 8 + 0) * 64 + lane) * 8);
        bnx[1][j4] = *(const bf16x8*)(wbp + (size_t)(((nt0 + j4) * 8 + 1) * 64 + lane) * 8);
      }
      #pragma unroll
      for (int ks = 0; ks < 8; ks++) {
        bf16x8 bc[2];
        #pragma unroll
        for (int j4 = 0; j4 < 2; j4++) bc[j4] = bnx[ks & 1][j4];
        if (ks < 6) {
          #pragma unroll
          for (int j4 = 0; j4 < 2; j4++)
            bnx[ks & 1][j4] = *(const bf16x8*)(wbp + (size_t)(((nt0 + j4) * 8 + ks + 2) * 64 + lane) * 8);
        }
        bf16x8 af[4];
        #pragma unroll
        for (int mt = 0; mt < 4; mt++)
          af[mt] = *(const bf16x8*)(spb + rowb[mt] + ks * 32 + lg * 8);
        __builtin_amdgcn_s_setprio(1);
        #pragma unroll
        for (int j4 = 0; j4 < 2; j4++)
          #pragma unroll
          for (int mt = 0; mt < 4; mt++)
            acc[mt][j4] = __builtin_amdgcn_mfma_f32_16x16x32_bf16(af[mt], bc[j4], acc[mt][j4], 0, 0, 0);
        __builtin_amdgcn_s_setprio(0);
      }
      if (jc < 2) {
        const int cb = jc * 32;
        #pragma unroll
        for (int mt = 0; mt < 4; mt++)
          #pragma unroll
          for (int reg = 0; reg < 4; reg++) {
            int rr = mt * 16 + lg * 4 + reg;
            if (rr < WS2) {
              #pragma unroll
              for (int j4 = 0; j4 < 2; j4++) {
                int c = cb + j4 * 16 + lm;
                myreg[rr * 64 + ((((c >> 3) ^ (rr & 7)) << 3) | (c & 7))] = f2bf(acc[mt][j4][reg]);
              }
            }
          }
      } else {
        // V -> packed bf16 registers (C layout: lane lm = d-col, rows lg*4+reg)
        #pragma unroll
        for (int mt = 0; mt < 4; mt++)
          #pragma unroll
          for (int j4 = 0; j4 < 2; j4++) {
            vpk[mt][j4][0] = pk2(acc[mt][j4][0], acc[mt][j4][1]);
            vpk[mt][j4][1] = pk2(acc[mt][j4][2], acc[mt][j4][3]);
          }
      }
    }

    // Q/K fragments from swizzled region (region dead after -> P overlay)
    bf16x8 qf[4], kf[4];
    #pragma unroll
    for (int t = 0; t < 4; t++) {
      int r = t * 16 + lm; if (r > 48) r = 48;
      const unsigned short* row = myreg + r * 64;
      qf[t] = *(const bf16x8*)(row + ((lg ^ (r & 7)) << 3));
      kf[t] = *(const bf16x8*)(row + (((4 + lg) ^ (r & 7)) << 3));
    }

    // S = Q K^T
    f32x4 s[4][4];
    __builtin_amdgcn_s_setprio(1);
    #pragma unroll
    for (int mt = 0; mt < 4; mt++)
      #pragma unroll
      for (int nt = 0; nt < 4; nt++) {
        s[mt][nt] = (f32x4){0.f, 0.f, 0.f, 0.f};
        s[mt][nt] = __builtin_amdgcn_mfma_f32_16x16x32_bf16(qf[mt], kf[nt], s[mt][nt], 0, 0, 0);
      }
    __builtin_amdgcn_s_setprio(0);
    #pragma unroll
    for (int mt = 0; mt < 4; mt++)
      #pragma unroll
      for (int nt = 0; nt < 4; nt++) {
        bool badcol = (nt == 3) && (lm > 0);
        #pragma unroll
        for (int reg = 0; reg < 4; reg++)
          s[mt][nt][reg] = badcol ? -1e30f : s[mt][nt][reg] * scale;
      }
    // softmax over keys (pos_bias cancels exactly)
    #pragma unroll
    for (int mt = 0; mt < 4; mt++) {
      #pragma unroll
      for (int reg = 0; reg < 4; reg++) {
        float mx = fmaxf(fmaxf(s[mt][0][reg], s[mt][1][reg]),
                         fmaxf(s[mt][2][reg], s[mt][3][reg]));
        #pragma unroll
        for (int off = 1; off < 16; off <<= 1) mx = fmaxf(mx, __shfl_xor(mx, off));
        float sum = 0.0f;
        #pragma unroll
        for (int nt = 0; nt < 4; nt++) {
          float e = __expf(s[mt][nt][reg] - mx);
          s[mt][nt][reg] = e;
          sum += e;
        }
        #pragma unroll
        for (int off = 1; off < 16; off <<= 1) sum += __shfl_xor(sum, off);
        float inv = 1.0f / sum;
        #pragma unroll
        for (int nt = 0; nt < 4; nt++) s[mt][nt][reg] *= inv;
      }
    }
    // P (bf16) -> swizzled region (overlays dead Q/K; same-wave ds order)
    #pragma unroll
    for (int mt = 0; mt < 4; mt++)
      #pragma unroll
      for (int nt = 0; nt < 4; nt++)
        #pragma unroll
        for (int reg = 0; reg < 4; reg++) {
          int p = mt * 16 + lg * 4 + reg;
          if (p < WS2) {
            int c = nt * 16 + lm;
            myreg[p * 64 + ((((c >> 3) ^ (p & 7)) << 3) | (c & 7))] = f2bf(s[mt][nt][reg]);
          }
        }
    // O = P V  (V fragments built in-register from vpk via shfl + bit_cast)
    f32x4 o[4][2];
    #pragma unroll
    for (int mt = 0; mt < 4; mt++)
      #pragma unroll
      for (int nt2 = 0; nt2 < 2; nt2++) o[mt][nt2] = (f32x4){0.f, 0.f, 0.f, 0.f};
    const int sA = (lane & 15) + ((lane >> 4) & 1) * 32;   // src lane, words 0,1
    const int sB = sA + 16;                                // src lane, words 2,3
    const int hi = (lane >> 5) & 1;                        // target lg>>1
    #pragma unroll
    for (int ks = 0; ks < 2; ks++) {
      bf16x8 vf[2];
      #pragma unroll
      for (int nt2 = 0; nt2 < 2; nt2++) {
        unsigned w0a = __shfl(vpk[2 * ks + 0][nt2][0], sA);
        unsigned w0b = __shfl(vpk[2 * ks + 1][nt2][0], sA);
        unsigned w1a = __shfl(vpk[2 * ks + 0][nt2][1], sA);
        unsigned w1b = __shfl(vpk[2 * ks + 1][nt2][1], sA);
        unsigned w2a = __shfl(vpk[2 * ks + 0][nt2][0], sB);
        unsigned w2b = __shfl(vpk[2 * ks + 1][nt2][0], sB);
        unsigned w3a = __shfl(vpk[2 * ks + 0][nt2][1], sB);
        unsigned w3b = __shfl(vpk[2 * ks + 1][nt2][1], sB);
        u32x4 uv;
        uv.x = hi ? w0b : w0a;
        uv.y = hi ? w1b : w1a;
        uv.z = hi ? w2b : w2a;
        uv.w = hi ? w3b : w3a;
        vf[nt2] = __builtin_bit_cast(bf16x8, uv);
      }
      __builtin_amdgcn_s_setprio(1);
      #pragma unroll
      for (int mt = 0; mt < 4; mt++) {
        int r = mt * 16 + lm; if (r > 48) r = 48;
        bf16x8 af = *(const bf16x8*)(myreg + r * 64 + (((ks * 4 + lg) ^ (r & 7)) << 3));
        #pragma unroll
        for (int nt2 = 0; nt2 < 2; nt2++)
          o[mt][nt2] = __builtin_amdgcn_mfma_f32_16x16x32_bf16(af, vf[nt2], o[mt][nt2], 0, 0, 0);
      }
      __builtin_amdgcn_s_setprio(0);
    }
    // O -> LDS assembly (P dead after PV), Ow stride 32 floats
    float* Ow = (float*)myreg;
    #pragma unroll
    for (int mt = 0; mt < 4; mt++)
      #pragma unroll
      for (int reg = 0; reg < 4; reg++) {
        int p = mt * 16 + lg * 4 + reg;
        if (p < WS2) {
          #pragma unroll
          for (int nt2 = 0; nt2 < 2; nt2++)
            Ow[p * 32 + nt2 * 16 + lm] = o[mt][nt2][reg];
        }
      }
    // pack bf16 + dense stores: contiguous 3136B run per head (r8-proven layout)
    unsigned short* ob16 = obase + (size_t)h * WS2 * HDD;
    for (int idx = lane; idx < WS2 * 4; idx += 64) {
      int p = idx >> 2, seg = idx & 3;
      const float* src = Ow + p * 32 + seg * 8;
      unsigned short o8[8];
      #pragma unroll
      for (int k = 0; k < 8; k++) o8[k] = f2bf(src[k]);
      *(uint4*)(ob16 + (size_t)idx * 8) = *(uint4*)o8;
    }
    // next pass's GEMM overwrites P/Ow (dead); same-wave ds program order
  }
}

// ---------- K3: conv + projection, 2 windows per block ----------
__global__ void k3_conv_proj(const unsigned short* __restrict__ o16,
                             const float* __restrict__ conv_w,
                             const float* __restrict__ conv_b,
                             const float* __restrict__ wpT,
                             const float* __restrict__ b_proj,
                             float* __restrict__ out) {
  __shared__ float yv[2][CC];
  __shared__ float cw[WS2];
  __shared__ int atab[2][392];
  const int tid = threadIdx.x;
  // bijective chunked swizzle over 300 (q=37, r=4): xcd<4 -> 38 ids, else 37
  const int orig = blockIdx.x;
  const int xcd = orig & 7;
  const int sub = orig >> 3;
  const int wg = (xcd < 4 ? xcd * 38 : 152 + (xcd - 4) * 37) + sub;
  const int np0 = wg * 2;
  const int b = blockIdx.y;
  if (tid < WS2) cw[tid] = conv_w[tid];
  for (int i = tid; i < 784; i += 256) {
    int which = (i >= 392) ? 1 : 0;
    int ii = i - which * 392;
    int Q = (np0 + which) * 392 + ii;
    int mq = Q % 600;
    int hp = Q / 600;
    atab[which][ii] = ((b * NWIN + mq) * 392 + hp) * 32;
  }
  __syncthreads();
  const int cg = tid >> 5, dd = tid & 31;
  float acc0 = conv_b[0], acc1 = conv_b[0];
  #pragma unroll 1
  for (int pb = 0; pb < 48; pb += 8) {
    float v0[8], v1[8];
    #pragma unroll
    for (int k = 0; k < 8; k++) {
      v0[k] = bf2f(o16[(size_t)atab[0][(pb + k) * 8 + cg] + dd]);
      v1[k] = bf2f(o16[(size_t)atab[1][(pb + k) * 8 + cg] + dd]);
    }
    #pragma unroll
    for (int k = 0; k < 8; k++) {
      acc0 += cw[pb + k] * v0[k];
      acc1 += cw[pb + k] * v1[k];
    }
  }
  acc0 += cw[48] * bf2f(o16[(size_t)atab[0][48 * 8 + cg] + dd]);
  acc1 += cw[48] * bf2f(o16[(size_t)atab[1][48 * 8 + cg] + dd]);
  yv[0][tid] = acc0;
  yv[1][tid] = acc1;
  __syncthreads();
  const float* wp = wpT + tid;
  float a0 = 0.0f, a1 = 0.0f, c0 = 0.0f, c1 = 0.0f;
  #pragma unroll 8
  for (int c = 0; c < CC; c += 2) {
    float w0 = wp[(c + 0) * CC];
    float w1 = wp[(c + 1) * CC];
    a0 += yv[0][c] * w0;  a1 += yv[0][c + 1] * w1;
    c0 += yv[1][c] * w0;  c1 += yv[1][c + 1] * w1;
  }
  float bp = b_proj[tid];
  out[((size_t)(b * NWIN + np0)) * CC + tid]     = bp + (a0 + a1);
  out[((size_t)(b * NWIN + np0 + 1)) * CC + tid] = bp + (c0 + c1);
}

extern "C" void kernel_launch(void* const* d_in, const int* in_sizes, int n_in,
                              void* d_out, int out_size, void* d_ws, size_t ws_size,
                              hipStream_t stream) {
  const float* x        = (const float*)d_in[0];
  const float* polys    = (const float*)d_in[1];
  const float* w_qkv    = (const float*)d_in[2];
  const float* b_qkv    = (const float*)d_in[3];
  const float* w_proj   = (const float*)d_in[4];
  const float* b_proj   = (const float*)d_in[5];
  const float* conv_w   = (const float*)d_in[6];
  const float* conv_b   = (const float*)d_in[7];
  float* out = (float*)d_out;

  char* ws = (char*)d_ws;
  float* xT = (float*)ws;
  unsigned short* wbp = (unsigned short*)(ws + XT_BYTES);
  float* wpT = (float*)(ws + XT_BYTES + WB_BYTES);
  unsigned short* o16 = (unsigned short*)(ws + XT_BYTES + WB_BYTES + WPT_BYTES);

  hipLaunchKernelGGL(k0_prep, dim3(673), dim3(256), 0, stream, x, xT, w_qkv, wbp, w_proj, wpT);
  hipLaunchKernelGGL(k12_fused, dim3(NWIN, B_), dim3(256), 0, stream,
                     xT, polys, wbp, b_qkv, o16);
  hipLaunchKernelGGL(k3_conv_proj, dim3(300, B_), dim3(256), 0, stream,
                     o16, conv_w, conv_b, wpT, b_proj, out);
}

// Round 18
// 159.252 us; speedup vs baseline: 1.0197x; 1.0197x over previous
//
#include <hip/hip_runtime.h>
#include <hip/hip_bf16.h>

// Problem constants
#define B_    2
#define QN    100
#define NP    6
#define WS2   49
#define CC    256
#define NHH   8
#define HDD   32
#define NWIN  600            // Q*Np windows per batch

// ws layout (bytes): xT fp32 (+1KB zero page) | wbp bf16 | wpT fp32 | o16 bf16
#define XT_BYTES   (8388608 + 1024)
#define ZABS       2097152                  // element index of the zero page in xT
#define WB_BYTES   393216
#define WPT_BYTES  262144

#define SPB_LD 264   // bf16 sp row stride (shorts)

// fused-kernel per-wave LDS region (single-head pass: Q|K 64 cols, Vt 32 rows)
#define QK_LD  72                  // Q|K row stride (64 cols + 8 pad), 144B, 16B-aligned
#define VT_LD  72                  // Vt row stride (shorts)
#define P_LD   72
#define OW_LD  36
#define QK_SHORTS   (WS2 * QK_LD)             // 3528 shorts (7056 B)
#define WREG_SHORTS (QK_SHORTS + 32 * VT_LD)  // + Vt 32 x 72 = 5832 shorts (11664 B)

typedef __attribute__((ext_vector_type(8))) short bf16x8;
typedef __attribute__((ext_vector_type(4))) float f32x4;

// RNE f32->bf16 via the HIP intrinsic (r16-proven: compiler emits native convert;
// hand-rolled bit-twiddle cost ~40 VGPR + 3 VALU/call). Same numerics.
__device__ __forceinline__ unsigned short f2bf(float f) {
  return __builtin_bit_cast(unsigned short, __float2bfloat16(f));
}
__device__ __forceinline__ float bf2f(unsigned short u) {
  union { unsigned int i; float f; } v; v.i = ((unsigned int)u) << 16; return v.f;
}

// ---------- K0: x-transpose float4 64x64 (0..511) + wbp pack (512..607)
//             + zero page (608) + w_proj transpose (609..672) ----------
__global__ void k0_prep(const float* __restrict__ x, float* __restrict__ xT,
                        const float* __restrict__ w_qkv, unsigned short* __restrict__ wbp,
                        const float* __restrict__ w_proj, float* __restrict__ wpT) {
  __shared__ float tile[64][65];
  const int gb = blockIdx.x;
  if (gb < 512) {
    // 64x64 tile, float4 on BOTH global sides (16B/lane)
    int b   = gb >> 8;
    int rem = gb & 255;              // 64 hw-tiles x 4 c-tiles
    int hw0 = (rem & 63) * 64;
    int c0  = (rem >> 6) * 64;
    int tx = threadIdx.x & 15, ty = threadIdx.x >> 4;   // 16x16
    const float* src = x + (size_t)b * CC * 4096;
    float* dst = xT + (size_t)b * 4096 * CC;
    #pragma unroll
    for (int i = 0; i < 4; i++) {
      int cl = ty + i * 16;
      float4 v = *(const float4*)(src + (size_t)(c0 + cl) * 4096 + hw0 + tx * 4);
      tile[tx * 4 + 0][cl] = v.x;
      tile[tx * 4 + 1][cl] = v.y;
      tile[tx * 4 + 2][cl] = v.z;
      tile[tx * 4 + 3][cl] = v.w;
    }
    __syncthreads();
    #pragma unroll
    for (int i = 0; i < 4; i++) {
      int hl = ty + i * 16;
      float4 v;
      v.x = tile[hl][tx * 4 + 0];
      v.y = tile[hl][tx * 4 + 1];
      v.z = tile[hl][tx * 4 + 2];
      v.w = tile[hl][tx * 4 + 3];
      *(float4*)(dst + (size_t)(hw0 + hl) * 256 + c0 + tx * 4) = v;
    }
  } else if (gb < 608) {
    // wbp[((nt*8+ks)*64+lane)*8+i] = bf16(w_qkv[nt*16+(lane&15)][ks*32+(lane>>4)*8+i])
    int g = (gb - 512) * 256 + threadIdx.x;       // 0..24575
    int lane = g & 63;
    int ks = (g >> 6) & 7;
    int nt = g >> 9;
    int n  = nt * 16 + (lane & 15);
    int k0 = ks * 32 + (lane >> 4) * 8;
    const float* src = w_qkv + (size_t)n * CC + k0;
    float4 lo = *(const float4*)(src);
    float4 hi = *(const float4*)(src + 4);
    unsigned short o[8] = { f2bf(lo.x), f2bf(lo.y), f2bf(lo.z), f2bf(lo.w),
                            f2bf(hi.x), f2bf(hi.y), f2bf(hi.z), f2bf(hi.w) };
    *(uint4*)(wbp + (size_t)g * 8) = *(uint4*)o;
  } else if (gb == 608) {
    xT[ZABS + threadIdx.x] = 0.0f;   // zero page for invalid bilinear corners
  } else {
    // wpT[c][j] = w_proj[j][c]
    int t = gb - 609;                // 0..63
    int r0 = (t >> 3) * 32;          // j tile
    int c0 = (t & 7) * 32;           // c tile
    int tx = threadIdx.x & 31, ty = threadIdx.x >> 5;
    #pragma unroll
    for (int i = ty; i < 32; i += 8)
      tile[i][tx] = w_proj[(size_t)(r0 + i) * CC + c0 + tx];
    __syncthreads();
    #pragma unroll
    for (int i = ty; i < 32; i += 8)
      wpT[(size_t)(c0 + i) * CC + r0 + tx] = tile[tx][i];
  }
}

// ---------- attention head body (k2-proven; single-head 32-row Vt) ----------
__device__ __forceinline__ void attn_head(
    const bf16x8 qf[4], const bf16x8 kf[4],
    unsigned short* P, const unsigned short* Vt, float* Ow, unsigned short* ob16,
    int lane, int lm, int lg) {
  const float scale = 0.17677669529663687f;  // 1/sqrt(32)
  // S = Q K^T  (setprio: favor MFMA-issuing wave over co-resident blocks' loads)
  f32x4 s[4][4];
  __builtin_amdgcn_s_setprio(1);
  #pragma unroll
  for (int mt = 0; mt < 4; mt++)
    #pragma unroll
    for (int nt = 0; nt < 4; nt++) {
      s[mt][nt] = (f32x4){0.f, 0.f, 0.f, 0.f};
      s[mt][nt] = __builtin_amdgcn_mfma_f32_16x16x32_bf16(qf[mt], kf[nt], s[mt][nt], 0, 0, 0);
    }
  __builtin_amdgcn_s_setprio(0);
  #pragma unroll
  for (int mt = 0; mt < 4; mt++)
    #pragma unroll
    for (int nt = 0; nt < 4; nt++) {
      bool badcol = (nt == 3) && (lm > 0);
      #pragma unroll
      for (int reg = 0; reg < 4; reg++)
        s[mt][nt][reg] = badcol ? -1e30f : s[mt][nt][reg] * scale;
    }
  // softmax over keys (pos_bias cancels exactly)
  #pragma unroll
  for (int mt = 0; mt < 4; mt++) {
    #pragma unroll
    for (int reg = 0; reg < 4; reg++) {
      float mx = fmaxf(fmaxf(s[mt][0][reg], s[mt][1][reg]),
                       fmaxf(s[mt][2][reg], s[mt][3][reg]));
      #pragma unroll
      for (int off = 1; off < 16; off <<= 1) mx = fmaxf(mx, __shfl_xor(mx, off));
      float sum = 0.0f;
      #pragma unroll
      for (int nt = 0; nt < 4; nt++) {
        float e = __expf(s[mt][nt][reg] - mx);
        s[mt][nt][reg] = e;
        sum += e;
      }
      #pragma unroll
      for (int off = 1; off < 16; off <<= 1) sum += __shfl_xor(sum, off);
      float inv = 1.0f / sum;
      #pragma unroll
      for (int nt = 0; nt < 4; nt++) s[mt][nt][reg] *= inv;
    }
  }
  // P (bf16) -> LDS row-major [p][r2]   (overlays dead Q/K region; same-wave order)
  #pragma unroll
  for (int mt = 0; mt < 4; mt++)
    #pragma unroll
    for (int nt = 0; nt < 4; nt++)
      #pragma unroll
      for (int reg = 0; reg < 4; reg++) {
        int p = mt * 16 + lg * 4 + reg;
        if (p < WS2) P[p * P_LD + nt * 16 + lm] = f2bf(s[mt][nt][reg]);
      }
  // O = P V
  f32x4 o[4][2];
  #pragma unroll
  for (int mt = 0; mt < 4; mt++)
    #pragma unroll
    for (int nt2 = 0; nt2 < 2; nt2++) o[mt][nt2] = (f32x4){0.f, 0.f, 0.f, 0.f};
  #pragma unroll
  for (int ks = 0; ks < 2; ks++) {
    bf16x8 vf[2];
    #pragma unroll
    for (int nt2 = 0; nt2 < 2; nt2++)
      vf[nt2] = *(const bf16x8*)(Vt + (nt2 * 16 + lm) * VT_LD + ks * 32 + lg * 8);
    __builtin_amdgcn_s_setprio(1);
    #pragma unroll
    for (int mt = 0; mt < 4; mt++) {
      bf16x8 af = *(const bf16x8*)(P + (mt * 16 + lm) * P_LD + ks * 32 + lg * 8);
      #pragma unroll
      for (int nt2 = 0; nt2 < 2; nt2++)
        o[mt][nt2] = __builtin_amdgcn_mfma_f32_16x16x32_bf16(af, vf[nt2], o[mt][nt2], 0, 0, 0);
    }
    __builtin_amdgcn_s_setprio(0);
  }
  // O -> LDS assembly (P region dead after PV)
  #pragma unroll
  for (int mt = 0; mt < 4; mt++)
    #pragma unroll
    for (int reg = 0; reg < 4; reg++) {
      int p = mt * 16 + lg * 4 + reg;
      if (p < WS2) {
        #pragma unroll
        for (int nt2 = 0; nt2 < 2; nt2++)
          Ow[p * OW_LD + nt2 * 16 + lm] = o[mt][nt2][reg];
      }
    }
  // pack bf16 + dense stores: contiguous 3136B run per head
  for (int idx = lane; idx < WS2 * 4; idx += 64) {
    int p = idx >> 2, seg = idx & 3;
    const float* src = Ow + p * OW_LD + seg * 8;
    unsigned short o8[8];
    #pragma unroll
    for (int k = 0; k < 8; k++) o8[k] = f2bf(src[k]);
    *(uint4*)(ob16 + (size_t)idx * 8) = *(uint4*)o8;
  }
}

// ---------- K12: fused sample + QKV GEMM + attention (r16 structure, final) ----------
__launch_bounds__(256, 2)
__global__ void k12_fused(const float* __restrict__ xT,
                          const float* __restrict__ polys,
                          const unsigned short* __restrict__ wbp,
                          const float* __restrict__ b_qkv,
                          unsigned short* __restrict__ o16) {
  __shared__ __align__(16) unsigned short spb[64 * SPB_LD];       // 33792 B
  __shared__ __align__(16) unsigned short wreg[4][WREG_SHORTS];   // 46656 B
  // co tables alias wave 0's Q|K region (dead until phase C; co dead after phase B)
  int*   co_off = (int*)&wreg[0][0];            // [49][4] ints, 784 B
  float* co_w   = (float*)&wreg[0][0] + 196;    // [49][4] floats, next 784 B
  const int tid = threadIdx.x;
  // XCD-chunked bijective swizzle (600 = 8*75)
  const int m = (blockIdx.x & 7) * 75 + (blockIdx.x >> 3);
  const int b = blockIdx.y;
  const int lane = tid & 63;
  const int wv = tid >> 6;
  const int lm = lane & 15;
  const int lg = lane >> 4;
  unsigned short* myq = &wreg[wv][0];
  unsigned short* VtW = myq + QK_SHORTS;

  // Phase A: per-row offsets + weights (grid scramble: n = m*49+r)
  if (tid < WS2) {
    int n = m * WS2 + tid;
    int q = n / (WS2 * NP);
    int p = (n / NP) % WS2;
    int a = n % NP;
    const float* pc = polys + (size_t)(b * QN + q) * 12;
    float al = (float)a * 0.2f;
    float py = pc[0];
    float px = pc[6];
    #pragma unroll
    for (int i = 1; i < 6; i++) { py = py * al + pc[i]; px = px * al + pc[6 + i]; }
    py = 2.0f * py - 1.0f;
    px = 2.0f * px - 1.0f;
    float gy = py + (2.0f * (-4.0f + (float)(p / 7) * (7.0f / 6.0f))) * (1.0f / 64.0f);
    float gx = px + (2.0f * (-4.0f + (float)(p % 7) * (7.0f / 6.0f))) * (1.0f / 64.0f);
    // NOTE the reference swap: fx from grid_y, fy from grid_x
    float fx = (gy + 1.0f) * 0.5f * 63.0f;
    float fy = (gx + 1.0f) * 0.5f * 63.0f;
    float x0 = floorf(fx), y0 = floorf(fy);
    float wx = fx - x0, wy = fy - y0;
    float x1 = x0 + 1.0f, y1 = y0 + 1.0f;
    int xi0 = (int)fminf(fmaxf(x0, 0.0f), 63.0f);
    int yi0 = (int)fminf(fmaxf(y0, 0.0f), 63.0f);
    int xi1 = (int)fminf(fmaxf(x1, 0.0f), 63.0f);
    int yi1 = (int)fminf(fmaxf(y1, 0.0f), 63.0f);
    bool vx0 = (x0 >= 0.0f) && (x0 <= 63.0f);
    bool vx1 = (x1 >= 0.0f) && (x1 <= 63.0f);
    bool vy0 = (y0 >= 0.0f) && (y0 <= 63.0f);
    bool vy1 = (y1 >= 0.0f) && (y1 <= 63.0f);
    const int bb = b * 4096;
    co_off[tid * 4 + 0] = (vx0 && vy0) ? (bb + yi0 * 64 + xi0) * CC : ZABS;
    co_off[tid * 4 + 1] = (vx1 && vy0) ? (bb + yi0 * 64 + xi1) * CC : ZABS;
    co_off[tid * 4 + 2] = (vx0 && vy1) ? (bb + yi1 * 64 + xi0) * CC : ZABS;
    co_off[tid * 4 + 3] = (vx1 && vy1) ? (bb + yi1 * 64 + xi1) * CC : ZABS;
    co_w[tid * 4 + 0] = (1.0f - wy) * (1.0f - wx);
    co_w[tid * 4 + 1] = (1.0f - wy) * wx;
    co_w[tid * 4 + 2] = wy * (1.0f - wx);
    co_w[tid * 4 + 3] = wy * wx;
  }
  // zero spb pad rows 49..63
  {
    unsigned int* z = (unsigned int*)(spb + WS2 * SPB_LD);
    for (int i = tid; i < 15 * SPB_LD / 2; i += 256) z[i] = 0u;
  }
  // zero own Vt region once (key cols 49..63 must stay 0 across both passes)
  {
    unsigned int* vz = (unsigned int*)VtW;
    #pragma unroll
    for (int i = 0; i < 18; i++) vz[i * 64 + lane] = 0u;
  }
  __syncthreads();

  // Phase B: bilinear sampling, thread = channel, batch-8 rows (32 loads in flight)
  for (int bi = 0; bi < 6; bi++) {
    const int rbase = bi * 8;
    float vv[8][4];
    #pragma unroll
    for (int k = 0; k < 8; k++) {
      int r = rbase + k;
      int4 off = *(const int4*)&co_off[r * 4];
      vv[k][0] = xT[off.x + tid];
      vv[k][1] = xT[off.y + tid];
      vv[k][2] = xT[off.z + tid];
      vv[k][3] = xT[off.w + tid];
    }
    #pragma unroll
    for (int k = 0; k < 8; k++) {
      int r = rbase + k;
      float4 w = *(const float4*)&co_w[r * 4];
      float s = vv[k][0] * w.x + vv[k][1] * w.y + vv[k][2] * w.z + vv[k][3] * w.w;
      spb[r * SPB_LD + tid] = f2bf(s);
    }
  }
  {  // tail row 48
    int4 off = *(const int4*)&co_off[48 * 4];
    float4 w = *(const float4*)&co_w[48 * 4];
    float s = xT[off.x + tid] * w.x + xT[off.y + tid] * w.y
            + xT[off.z + tid] * w.z + xT[off.w + tid] * w.w;
    spb[48 * SPB_LD + tid] = f2bf(s);
  }
  __syncthreads();

  unsigned short* obase = o16 + (size_t)(b * NWIN + m) * 392 * 32;

  // Two single-head passes: h = 2*wv + hp
  for (int hp = 0; hp < 2; hp++) {
    const int h = 2 * wv + hp;
    // GEMM: jc=0 -> Q (local cols 0..31), jc=1 -> K (32..63), jc=2 -> V (transpose to Vt)
    for (int jc = 0; jc < 3; jc++) {
      const int nt0 = jc * 16 + 2 * h;
      f32x4 acc[4][2];
      #pragma unroll
      for (int j4 = 0; j4 < 2; j4++) {
        float bias = b_qkv[(nt0 + j4) * 16 + lm];
        #pragma unroll
        for (int mt = 0; mt < 4; mt++) acc[mt][j4] = (f32x4){bias, bias, bias, bias};
      }
      // 2-deep register prefetch for B fragments (r8-proven, +8 VGPR only)
      bf16x8 bnx[2][2];   // [ks parity][j4]
      #pragma unroll
      for (int j4 = 0; j4 < 2; j4++) {
        bnx[0][j4] = *(const bf16x8*)(wbp + (size_t)(((nt0 + j4) * 8 + 0) * 64 + lane) * 8);
        bnx[1][j4] = *(const bf16x8*)(wbp + (size_t)(((nt0 + j4) * 8 + 1) * 64 + lane) * 8);
      }
      #pragma unroll
      for (int ks = 0; ks < 8; ks++) {
        bf16x8 bc[2];
        #pragma unroll
        for (int j4 = 0; j4 < 2; j4++) bc[j4] = bnx[ks & 1][j4];
        if (ks < 6) {
          #pragma unroll
          for (int j4 = 0; j4 < 2; j4++)
            bnx[ks & 1][j4] = *(const bf16x8*)(wbp + (size_t)(((nt0 + j4) * 8 + ks + 2) * 64 + lane) * 8);
        }
        bf16x8 af[4];
        #pragma unroll
        for (int mt = 0; mt < 4; mt++)
          af[mt] = *(const bf16x8*)(spb + (mt * 16 + lm) * SPB_LD + ks * 32 + lg * 8);
        __builtin_amdgcn_s_setprio(1);
        #pragma unroll
        for (int j4 = 0; j4 < 2; j4++)
          #pragma unroll
          for (int mt = 0; mt < 4; mt++)
            acc[mt][j4] = __builtin_amdgcn_mfma_f32_16x16x32_bf16(af[mt], bc[j4], acc[mt][j4], 0, 0, 0);
        __builtin_amdgcn_s_setprio(0);
      }
      if (jc < 2) {
        const int cb = jc * 32;
        #pragma unroll
        for (int mt = 0; mt < 4; mt++)
          #pragma unroll
          for (int reg = 0; reg < 4; reg++) {
            int rr = mt * 16 + lg * 4 + reg;
            if (rr < WS2) {
              #pragma unroll
              for (int j4 = 0; j4 < 2; j4++)
                myq[rr * QK_LD + cb + j4 * 16 + lm] = f2bf(acc[mt][j4][reg]);
            }
          }
      } else {
        // V direct transpose: Vt[d][r], d = j4*16+lm in [0,32)
        #pragma unroll
        for (int mt = 0; mt < 4; mt++)
          #pragma unroll
          for (int reg = 0; reg < 4; reg++) {
            int rr = mt * 16 + lg * 4 + reg;
            if (rr < WS2) {
              #pragma unroll
              for (int j4 = 0; j4 < 2; j4++)
                VtW[(j4 * 16 + lm) * VT_LD + rr] = f2bf(acc[mt][j4][reg]);
            }
          }
      }
    }

    // Q/K fragments from own LDS region (then region is dead -> P/Ow overlay)
    bf16x8 qf[4], kf[4];
    #pragma unroll
    for (int t = 0; t < 4; t++) {
      int r = t * 16 + lm; if (r > 48) r = 48;
      const unsigned short* row = myq + r * QK_LD;
      qf[t] = *(const bf16x8*)(row + lg * 8);
      kf[t] = *(const bf16x8*)(row + 32 + lg * 8);
    }
    unsigned short* P = myq;       // overlays dead Q/K region (same-wave ds order)
    float* Ow = (float*)myq;
    attn_head(qf, kf, P, VtW, Ow,
              obase + (size_t)h * WS2 * HDD, lane, lm, lg);
    // pass 1 GEMM overwrites P/Ow (dead) and Vt rows r<49 (dead); same-wave order
  }
}

// ---------- K3: conv + projection, 2 windows per block ----------
__global__ void k3_conv_proj(const unsigned short* __restrict__ o16,
                             const float* __restrict__ conv_w,
                             const float* __restrict__ conv_b,
                             const float* __restrict__ wpT,
                             const float* __restrict__ b_proj,
                             float* __restrict__ out) {
  __shared__ float yv[2][CC];
  __shared__ float cw[WS2];
  __shared__ int atab[2][392];
  const int tid = threadIdx.x;
  // bijective chunked swizzle over 300 (q=37, r=4): xcd<4 -> 38 ids, else 37
  const int orig = blockIdx.x;
  const int xcd = orig & 7;
  const int sub = orig >> 3;
  const int wg = (xcd < 4 ? xcd * 38 : 152 + (xcd - 4) * 37) + sub;
  const int np0 = wg * 2;
  const int b = blockIdx.y;
  if (tid < WS2) cw[tid] = conv_w[tid];
  for (int i = tid; i < 784; i += 256) {
    int which = (i >= 392) ? 1 : 0;
    int ii = i - which * 392;
    int Q = (np0 + which) * 392 + ii;
    int mq = Q % 600;
    int hp = Q / 600;
    atab[which][ii] = ((b * NWIN + mq) * 392 + hp) * 32;
  }
  __syncthreads();
  const int cg = tid >> 5, dd = tid & 31;
  float acc0 = conv_b[0], acc1 = conv_b[0];
  #pragma unroll 1
  for (int pb = 0; pb < 48; pb += 8) {
    float v0[8], v1[8];
    #pragma unroll
    for (int k = 0; k < 8; k++) {
      v0[k] = bf2f(o16[(size_t)atab[0][(pb + k) * 8 + cg] + dd]);
      v1[k] = bf2f(o16[(size_t)atab[1][(pb + k) * 8 + cg] + dd]);
    }
    #pragma unroll
    for (int k = 0; k < 8; k++) {
      acc0 += cw[pb + k] * v0[k];
      acc1 += cw[pb + k] * v1[k];
    }
  }
  acc0 += cw[48] * bf2f(o16[(size_t)atab[0][48 * 8 + cg] + dd]);
  acc1 += cw[48] * bf2f(o16[(size_t)atab[1][48 * 8 + cg] + dd]);
  yv[0][tid] = acc0;
  yv[1][tid] = acc1;
  __syncthreads();
  const float* wp = wpT + tid;
  float a0 = 0.0f, a1 = 0.0f, c0 = 0.0f, c1 = 0.0f;
  #pragma unroll 8
  for (int c = 0; c < CC; c += 2) {
    float w0 = wp[(c + 0) * CC];
    float w1 = wp[(c + 1) * CC];
    a0 += yv[0][c] * w0;  a1 += yv[0][c + 1] * w1;
    c0 += yv[1][c] * w0;  c1 += yv[1][c + 1] * w1;
  }
  float bp = b_proj[tid];
  out[((size_t)(b * NWIN + np0)) * CC + tid]     = bp + (a0 + a1);
  out[((size_t)(b * NWIN + np0 + 1)) * CC + tid] = bp + (c0 + c1);
}

extern "C" void kernel_launch(void* const* d_in, const int* in_sizes, int n_in,
                              void* d_out, int out_size, void* d_ws, size_t ws_size,
                              hipStream_t stream) {
  const float* x        = (const float*)d_in[0];
  const float* polys    = (const float*)d_in[1];
  const float* w_qkv    = (const float*)d_in[2];
  const float* b_qkv    = (const float*)d_in[3];
  const float* w_proj   = (const float*)d_in[4];
  const float* b_proj   = (const float*)d_in[5];
  const float* conv_w   = (const float*)d_in[6];
  const float* conv_b   = (const float*)d_in[7];
  float* out = (float*)d_out;

  char* ws = (char*)d_ws;
  float* xT = (float*)ws;
  unsigned short* wbp = (unsigned short*)(ws + XT_BYTES);
  float* wpT = (float*)(ws + XT_BYTES + WB_BYTES);
  unsigned short* o16 = (unsigned short*)(ws + XT_BYTES + WB_BYTES + WPT_BYTES);

  hipLaunchKernelGGL(k0_prep, dim3(673), dim3(256), 0, stream, x, xT, w_qkv, wbp, w_proj, wpT);
  hipLaunchKernelGGL(k12_fused, dim3(NWIN, B_), dim3(256), 0, stream,
                     xT, polys, wbp, b_qkv, o16);
  hipLaunchKernelGGL(k3_conv_proj, dim3(300, B_), dim3(256), 0, stream,
                     o16, conv_w, conv_b, wpT, b_proj, out);
}

// Round 19
// 157.409 us; speedup vs baseline: 1.0316x; 1.0117x over previous
//
#include <hip/hip_runtime.h>
#include <hip/hip_bf16.h>

// Problem constants
#define B_    2
#define QN    100
#define NP    6
#define WS2   49
#define CC    256
#define NHH   8
#define HDD   32
#define NWIN  600            // Q*Np windows per batch

// ws layout (bytes): xT fp32 (+1KB zero page) | wbp bf16 | wpT fp32 | o16 bf16
#define XT_BYTES   (8388608 + 1024)
#define ZABS       2097152                  // element index of the zero page in xT
#define WB_BYTES   393216
#define WPT_BYTES  262144

#define SPB_LD 264   // bf16 sp row stride (shorts)

// fused-kernel per-wave LDS region (single-head pass: Q|K 64 cols, Vt 32 rows)
#define QK_LD  72                  // Q|K row stride (64 cols + 8 pad), 144B, 16B-aligned
#define VT_LD  72                  // Vt row stride (shorts)
#define P_LD   72
#define OW_LD  36
#define QK_SHORTS   (WS2 * QK_LD)             // 3528 shorts (7056 B)
#define WREG_SHORTS (QK_SHORTS + 32 * VT_LD)  // + Vt 32 x 72 = 5832 shorts (11664 B)

typedef __attribute__((ext_vector_type(8))) short bf16x8;
typedef __attribute__((ext_vector_type(4))) float f32x4;

// RNE f32->bf16 via the HIP intrinsic (r16-proven: compiler emits native convert;
// hand-rolled bit-twiddle cost ~40 VGPR + 3 VALU/call). Same numerics.
__device__ __forceinline__ unsigned short f2bf(float f) {
  return __builtin_bit_cast(unsigned short, __float2bfloat16(f));
}
__device__ __forceinline__ float bf2f(unsigned short u) {
  union { unsigned int i; float f; } v; v.i = ((unsigned int)u) << 16; return v.f;
}

// ---------- K0: x-transpose float4 64x64 (0..511) + wbp pack (512..607)
//             + zero page (608) + w_proj transpose (609..672) ----------
__global__ void k0_prep(const float* __restrict__ x, float* __restrict__ xT,
                        const float* __restrict__ w_qkv, unsigned short* __restrict__ wbp,
                        const float* __restrict__ w_proj, float* __restrict__ wpT) {
  __shared__ float tile[64][65];
  const int gb = blockIdx.x;
  if (gb < 512) {
    // 64x64 tile, float4 on BOTH global sides (16B/lane)
    int b   = gb >> 8;
    int rem = gb & 255;              // 64 hw-tiles x 4 c-tiles
    int hw0 = (rem & 63) * 64;
    int c0  = (rem >> 6) * 64;
    int tx = threadIdx.x & 15, ty = threadIdx.x >> 4;   // 16x16
    const float* src = x + (size_t)b * CC * 4096;
    float* dst = xT + (size_t)b * 4096 * CC;
    #pragma unroll
    for (int i = 0; i < 4; i++) {
      int cl = ty + i * 16;
      float4 v = *(const float4*)(src + (size_t)(c0 + cl) * 4096 + hw0 + tx * 4);
      tile[tx * 4 + 0][cl] = v.x;
      tile[tx * 4 + 1][cl] = v.y;
      tile[tx * 4 + 2][cl] = v.z;
      tile[tx * 4 + 3][cl] = v.w;
    }
    __syncthreads();
    #pragma unroll
    for (int i = 0; i < 4; i++) {
      int hl = ty + i * 16;
      float4 v;
      v.x = tile[hl][tx * 4 + 0];
      v.y = tile[hl][tx * 4 + 1];
      v.z = tile[hl][tx * 4 + 2];
      v.w = tile[hl][tx * 4 + 3];
      *(float4*)(dst + (size_t)(hw0 + hl) * 256 + c0 + tx * 4) = v;
    }
  } else if (gb < 608) {
    // wbp[((nt*8+ks)*64+lane)*8+i] = bf16(w_qkv[nt*16+(lane&15)][ks*32+(lane>>4)*8+i])
    int g = (gb - 512) * 256 + threadIdx.x;       // 0..24575
    int lane = g & 63;
    int ks = (g >> 6) & 7;
    int nt = g >> 9;
    int n  = nt * 16 + (lane & 15);
    int k0 = ks * 32 + (lane >> 4) * 8;
    const float* src = w_qkv + (size_t)n * CC + k0;
    float4 lo = *(const float4*)(src);
    float4 hi = *(const float4*)(src + 4);
    unsigned short o[8] = { f2bf(lo.x), f2bf(lo.y), f2bf(lo.z), f2bf(lo.w),
                            f2bf(hi.x), f2bf(hi.y), f2bf(hi.z), f2bf(hi.w) };
    *(uint4*)(wbp + (size_t)g * 8) = *(uint4*)o;
  } else if (gb == 608) {
    xT[ZABS + threadIdx.x] = 0.0f;   // zero page for invalid bilinear corners
  } else {
    // wpT[c][j] = w_proj[j][c]
    int t = gb - 609;                // 0..63
    int r0 = (t >> 3) * 32;          // j tile
    int c0 = (t & 7) * 32;           // c tile
    int tx = threadIdx.x & 31, ty = threadIdx.x >> 5;
    #pragma unroll
    for (int i = ty; i < 32; i += 8)
      tile[i][tx] = w_proj[(size_t)(r0 + i) * CC + c0 + tx];
    __syncthreads();
    #pragma unroll
    for (int i = ty; i < 32; i += 8)
      wpT[(size_t)(c0 + i) * CC + r0 + tx] = tile[tx][i];
  }
}

// ---------- attention head body (k2-proven; single-head 32-row Vt) ----------
__device__ __forceinline__ void attn_head(
    const bf16x8 qf[4], const bf16x8 kf[4],
    unsigned short* P, const unsigned short* Vt, float* Ow, unsigned short* ob16,
    int lane, int lm, int lg) {
  const float scale = 0.17677669529663687f;  // 1/sqrt(32)
  // S = Q K^T  (setprio: favor MFMA-issuing wave over co-resident blocks' loads)
  f32x4 s[4][4];
  __builtin_amdgcn_s_setprio(1);
  #pragma unroll
  for (int mt = 0; mt < 4; mt++)
    #pragma unroll
    for (int nt = 0; nt < 4; nt++) {
      s[mt][nt] = (f32x4){0.f, 0.f, 0.f, 0.f};
      s[mt][nt] = __builtin_amdgcn_mfma_f32_16x16x32_bf16(qf[mt], kf[nt], s[mt][nt], 0, 0, 0);
    }
  __builtin_amdgcn_s_setprio(0);
  #pragma unroll
  for (int mt = 0; mt < 4; mt++)
    #pragma unroll
    for (int nt = 0; nt < 4; nt++) {
      bool badcol = (nt == 3) && (lm > 0);
      #pragma unroll
      for (int reg = 0; reg < 4; reg++)
        s[mt][nt][reg] = badcol ? -1e30f : s[mt][nt][reg] * scale;
    }
  // softmax over keys (pos_bias cancels exactly)
  #pragma unroll
  for (int mt = 0; mt < 4; mt++) {
    #pragma unroll
    for (int reg = 0; reg < 4; reg++) {
      float mx = fmaxf(fmaxf(s[mt][0][reg], s[mt][1][reg]),
                       fmaxf(s[mt][2][reg], s[mt][3][reg]));
      #pragma unroll
      for (int off = 1; off < 16; off <<= 1) mx = fmaxf(mx, __shfl_xor(mx, off));
      float sum = 0.0f;
      #pragma unroll
      for (int nt = 0; nt < 4; nt++) {
        float e = __expf(s[mt][nt][reg] - mx);
        s[mt][nt][reg] = e;
        sum += e;
      }
      #pragma unroll
      for (int off = 1; off < 16; off <<= 1) sum += __shfl_xor(sum, off);
      float inv = 1.0f / sum;
      #pragma unroll
      for (int nt = 0; nt < 4; nt++) s[mt][nt][reg] *= inv;
    }
  }
  // P (bf16) -> LDS row-major [p][r2]   (overlays dead Q/K region; same-wave order)
  #pragma unroll
  for (int mt = 0; mt < 4; mt++)
    #pragma unroll
    for (int nt = 0; nt < 4; nt++)
      #pragma unroll
      for (int reg = 0; reg < 4; reg++) {
        int p = mt * 16 + lg * 4 + reg;
        if (p < WS2) P[p * P_LD + nt * 16 + lm] = f2bf(s[mt][nt][reg]);
      }
  // O = P V
  f32x4 o[4][2];
  #pragma unroll
  for (int mt = 0; mt < 4; mt++)
    #pragma unroll
    for (int nt2 = 0; nt2 < 2; nt2++) o[mt][nt2] = (f32x4){0.f, 0.f, 0.f, 0.f};
  #pragma unroll
  for (int ks = 0; ks < 2; ks++) {
    bf16x8 vf[2];
    #pragma unroll
    for (int nt2 = 0; nt2 < 2; nt2++)
      vf[nt2] = *(const bf16x8*)(Vt + (nt2 * 16 + lm) * VT_LD + ks * 32 + lg * 8);
    __builtin_amdgcn_s_setprio(1);
    #pragma unroll
    for (int mt = 0; mt < 4; mt++) {
      bf16x8 af = *(const bf16x8*)(P + (mt * 16 + lm) * P_LD + ks * 32 + lg * 8);
      #pragma unroll
      for (int nt2 = 0; nt2 < 2; nt2++)
        o[mt][nt2] = __builtin_amdgcn_mfma_f32_16x16x32_bf16(af, vf[nt2], o[mt][nt2], 0, 0, 0);
    }
    __builtin_amdgcn_s_setprio(0);
  }
  // O -> LDS assembly (P region dead after PV)
  #pragma unroll
  for (int mt = 0; mt < 4; mt++)
    #pragma unroll
    for (int reg = 0; reg < 4; reg++) {
      int p = mt * 16 + lg * 4 + reg;
      if (p < WS2) {
        #pragma unroll
        for (int nt2 = 0; nt2 < 2; nt2++)
          Ow[p * OW_LD + nt2 * 16 + lm] = o[mt][nt2][reg];
      }
    }
  // pack bf16 + dense stores: contiguous 3136B run per head
  for (int idx = lane; idx < WS2 * 4; idx += 64) {
    int p = idx >> 2, seg = idx & 3;
    const float* src = Ow + p * OW_LD + seg * 8;
    unsigned short o8[8];
    #pragma unroll
    for (int k = 0; k < 8; k++) o8[k] = f2bf(src[k]);
    *(uint4*)(ob16 + (size_t)idx * 8) = *(uint4*)o8;
  }
}

// ---------- K12: fused sample + QKV GEMM + attention (final verified config) ----------
__launch_bounds__(256, 2)
__global__ void k12_fused(const float* __restrict__ xT,
                          const float* __restrict__ polys,
                          const unsigned short* __restrict__ wbp,
                          const float* __restrict__ b_qkv,
                          unsigned short* __restrict__ o16) {
  __shared__ __align__(16) unsigned short spb[64 * SPB_LD];       // 33792 B
  __shared__ __align__(16) unsigned short wreg[4][WREG_SHORTS];   // 46656 B
  // co tables alias wave 0's Q|K region (dead until phase C; co dead after phase B)
  int*   co_off = (int*)&wreg[0][0];            // [49][4] ints, 784 B
  float* co_w   = (float*)&wreg[0][0] + 196;    // [49][4] floats, next 784 B
  const int tid = threadIdx.x;
  // XCD-chunked bijective swizzle (600 = 8*75)
  const int m = (blockIdx.x & 7) * 75 + (blockIdx.x >> 3);
  const int b = blockIdx.y;
  const int lane = tid & 63;
  const int wv = tid >> 6;
  const int lm = lane & 15;
  const int lg = lane >> 4;
  unsigned short* myq = &wreg[wv][0];
  unsigned short* VtW = myq + QK_SHORTS;

  // Phase A: per-row offsets + weights (grid scramble: n = m*49+r)
  if (tid < WS2) {
    int n = m * WS2 + tid;
    int q = n / (WS2 * NP);
    int p = (n / NP) % WS2;
    int a = n % NP;
    const float* pc = polys + (size_t)(b * QN + q) * 12;
    float al = (float)a * 0.2f;
    float py = pc[0];
    float px = pc[6];
    #pragma unroll
    for (int i = 1; i < 6; i++) { py = py * al + pc[i]; px = px * al + pc[6 + i]; }
    py = 2.0f * py - 1.0f;
    px = 2.0f * px - 1.0f;
    float gy = py + (2.0f * (-4.0f + (float)(p / 7) * (7.0f / 6.0f))) * (1.0f / 64.0f);
    float gx = px + (2.0f * (-4.0f + (float)(p % 7) * (7.0f / 6.0f))) * (1.0f / 64.0f);
    // NOTE the reference swap: fx from grid_y, fy from grid_x
    float fx = (gy + 1.0f) * 0.5f * 63.0f;
    float fy = (gx + 1.0f) * 0.5f * 63.0f;
    float x0 = floorf(fx), y0 = floorf(fy);
    float wx = fx - x0, wy = fy - y0;
    float x1 = x0 + 1.0f, y1 = y0 + 1.0f;
    int xi0 = (int)fminf(fmaxf(x0, 0.0f), 63.0f);
    int yi0 = (int)fminf(fmaxf(y0, 0.0f), 63.0f);
    int xi1 = (int)fminf(fmaxf(x1, 0.0f), 63.0f);
    int yi1 = (int)fminf(fmaxf(y1, 0.0f), 63.0f);
    bool vx0 = (x0 >= 0.0f) && (x0 <= 63.0f);
    bool vx1 = (x1 >= 0.0f) && (x1 <= 63.0f);
    bool vy0 = (y0 >= 0.0f) && (y0 <= 63.0f);
    bool vy1 = (y1 >= 0.0f) && (y1 <= 63.0f);
    const int bb = b * 4096;
    co_off[tid * 4 + 0] = (vx0 && vy0) ? (bb + yi0 * 64 + xi0) * CC : ZABS;
    co_off[tid * 4 + 1] = (vx1 && vy0) ? (bb + yi0 * 64 + xi1) * CC : ZABS;
    co_off[tid * 4 + 2] = (vx0 && vy1) ? (bb + yi1 * 64 + xi0) * CC : ZABS;
    co_off[tid * 4 + 3] = (vx1 && vy1) ? (bb + yi1 * 64 + xi1) * CC : ZABS;
    co_w[tid * 4 + 0] = (1.0f - wy) * (1.0f - wx);
    co_w[tid * 4 + 1] = (1.0f - wy) * wx;
    co_w[tid * 4 + 2] = wy * (1.0f - wx);
    co_w[tid * 4 + 3] = wy * wx;
  }
  // zero spb pad rows 49..63
  {
    unsigned int* z = (unsigned int*)(spb + WS2 * SPB_LD);
    for (int i = tid; i < 15 * SPB_LD / 2; i += 256) z[i] = 0u;
  }
  // zero own Vt region once (key cols 49..63 must stay 0 across both passes)
  {
    unsigned int* vz = (unsigned int*)VtW;
    #pragma unroll
    for (int i = 0; i < 18; i++) vz[i * 64 + lane] = 0u;
  }
  __syncthreads();

  // Phase B: bilinear sampling, thread = channel, batch-8 rows (32 loads in flight)
  for (int bi = 0; bi < 6; bi++) {
    const int rbase = bi * 8;
    float vv[8][4];
    #pragma unroll
    for (int k = 0; k < 8; k++) {
      int r = rbase + k;
      int4 off = *(const int4*)&co_off[r * 4];
      vv[k][0] = xT[off.x + tid];
      vv[k][1] = xT[off.y + tid];
      vv[k][2] = xT[off.z + tid];
      vv[k][3] = xT[off.w + tid];
    }
    #pragma unroll
    for (int k = 0; k < 8; k++) {
      int r = rbase + k;
      float4 w = *(const float4*)&co_w[r * 4];
      float s = vv[k][0] * w.x + vv[k][1] * w.y + vv[k][2] * w.z + vv[k][3] * w.w;
      spb[r * SPB_LD + tid] = f2bf(s);
    }
  }
  {  // tail row 48
    int4 off = *(const int4*)&co_off[48 * 4];
    float4 w = *(const float4*)&co_w[48 * 4];
    float s = xT[off.x + tid] * w.x + xT[off.y + tid] * w.y
            + xT[off.z + tid] * w.z + xT[off.w + tid] * w.w;
    spb[48 * SPB_LD + tid] = f2bf(s);
  }
  __syncthreads();

  unsigned short* obase = o16 + (size_t)(b * NWIN + m) * 392 * 32;

  // Two single-head passes: h = 2*wv + hp
  for (int hp = 0; hp < 2; hp++) {
    const int h = 2 * wv + hp;
    // GEMM: jc=0 -> Q (local cols 0..31), jc=1 -> K (32..63), jc=2 -> V (transpose to Vt)
    for (int jc = 0; jc < 3; jc++) {
      const int nt0 = jc * 16 + 2 * h;
      f32x4 acc[4][2];
      #pragma unroll
      for (int j4 = 0; j4 < 2; j4++) {
        float bias = b_qkv[(nt0 + j4) * 16 + lm];
        #pragma unroll
        for (int mt = 0; mt < 4; mt++) acc[mt][j4] = (f32x4){bias, bias, bias, bias};
      }
      // 2-deep register prefetch for B fragments (r8-proven, +8 VGPR only)
      bf16x8 bnx[2][2];   // [ks parity][j4]
      #pragma unroll
      for (int j4 = 0; j4 < 2; j4++) {
        bnx[0][j4] = *(const bf16x8*)(wbp + (size_t)(((nt0 + j4) * 8 + 0) * 64 + lane) * 8);
        bnx[1][j4] = *(const bf16x8*)(wbp + (size_t)(((nt0 + j4) * 8 + 1) * 64 + lane) * 8);
      }
      #pragma unroll
      for (int ks = 0; ks < 8; ks++) {
        bf16x8 bc[2];
        #pragma unroll
        for (int j4 = 0; j4 < 2; j4++) bc[j4] = bnx[ks & 1][j4];
        if (ks < 6) {
          #pragma unroll
          for (int j4 = 0; j4 < 2; j4++)
            bnx[ks & 1][j4] = *(const bf16x8*)(wbp + (size_t)(((nt0 + j4) * 8 + ks + 2) * 64 + lane) * 8);
        }
        bf16x8 af[4];
        #pragma unroll
        for (int mt = 0; mt < 4; mt++)
          af[mt] = *(const bf16x8*)(spb + (mt * 16 + lm) * SPB_LD + ks * 32 + lg * 8);
        __builtin_amdgcn_s_setprio(1);
        #pragma unroll
        for (int j4 = 0; j4 < 2; j4++)
          #pragma unroll
          for (int mt = 0; mt < 4; mt++)
            acc[mt][j4] = __builtin_amdgcn_mfma_f32_16x16x32_bf16(af[mt], bc[j4], acc[mt][j4], 0, 0, 0);
        __builtin_amdgcn_s_setprio(0);
      }
      if (jc < 2) {
        const int cb = jc * 32;
        #pragma unroll
        for (int mt = 0; mt < 4; mt++)
          #pragma unroll
          for (int reg = 0; reg < 4; reg++) {
            int rr = mt * 16 + lg * 4 + reg;
            if (rr < WS2) {
              #pragma unroll
              for (int j4 = 0; j4 < 2; j4++)
                myq[rr * QK_LD + cb + j4 * 16 + lm] = f2bf(acc[mt][j4][reg]);
            }
          }
      } else {
        // V direct transpose: Vt[d][r], d = j4*16+lm in [0,32)
        #pragma unroll
        for (int mt = 0; mt < 4; mt++)
          #pragma unroll
          for (int reg = 0; reg < 4; reg++) {
            int rr = mt * 16 + lg * 4 + reg;
            if (rr < WS2) {
              #pragma unroll
              for (int j4 = 0; j4 < 2; j4++)
                VtW[(j4 * 16 + lm) * VT_LD + rr] = f2bf(acc[mt][j4][reg]);
            }
          }
      }
    }

    // Q/K fragments from own LDS region (then region is dead -> P/Ow overlay)
    bf16x8 qf[4], kf[4];
    #pragma unroll
    for (int t = 0; t < 4; t++) {
      int r = t * 16 + lm; if (r > 48) r = 48;
      const unsigned short* row = myq + r * QK_LD;
      qf[t] = *(const bf16x8*)(row + lg * 8);
      kf[t] = *(const bf16x8*)(row + 32 + lg * 8);
    }
    unsigned short* P = myq;       // overlays dead Q/K region (same-wave ds order)
    float* Ow = (float*)myq;
    attn_head(qf, kf, P, VtW, Ow,
              obase + (size_t)h * WS2 * HDD, lane, lm, lg);
    // pass 1 GEMM overwrites P/Ow (dead) and Vt rows r<49 (dead); same-wave order
  }
}

// ---------- K3: conv + projection, 2 windows per block ----------
__global__ void k3_conv_proj(const unsigned short* __restrict__ o16,
                             const float* __restrict__ conv_w,
                             const float* __restrict__ conv_b,
                             const float* __restrict__ wpT,
                             const float* __restrict__ b_proj,
                             float* __restrict__ out) {
  __shared__ float yv[2][CC];
  __shared__ float cw[WS2];
  __shared__ int atab[2][392];
  const int tid = threadIdx.x;
  // bijective chunked swizzle over 300 (q=37, r=4): xcd<4 -> 38 ids, else 37
  const int orig = blockIdx.x;
  const int xcd = orig & 7;
  const int sub = orig >> 3;
  const int wg = (xcd < 4 ? xcd * 38 : 152 + (xcd - 4) * 37) + sub;
  const int np0 = wg * 2;
  const int b = blockIdx.y;
  if (tid < WS2) cw[tid] = conv_w[tid];
  for (int i = tid; i < 784; i += 256) {
    int which = (i >= 392) ? 1 : 0;
    int ii = i - which * 392;
    int Q = (np0 + which) * 392 + ii;
    int mq = Q % 600;
    int hp = Q / 600;
    atab[which][ii] = ((b * NWIN + mq) * 392 + hp) * 32;
  }
  __syncthreads();
  const int cg = tid >> 5, dd = tid & 31;
  float acc0 = conv_b[0], acc1 = conv_b[0];
  #pragma unroll 1
  for (int pb = 0; pb < 48; pb += 8) {
    float v0[8], v1[8];
    #pragma unroll
    for (int k = 0; k < 8; k++) {
      v0[k] = bf2f(o16[(size_t)atab[0][(pb + k) * 8 + cg] + dd]);
      v1[k] = bf2f(o16[(size_t)atab[1][(pb + k) * 8 + cg] + dd]);
    }
    #pragma unroll
    for (int k = 0; k < 8; k++) {
      acc0 += cw[pb + k] * v0[k];
      acc1 += cw[pb + k] * v1[k];
    }
  }
  acc0 += cw[48] * bf2f(o16[(size_t)atab[0][48 * 8 + cg] + dd]);
  acc1 += cw[48] * bf2f(o16[(size_t)atab[1][48 * 8 + cg] + dd]);
  yv[0][tid] = acc0;
  yv[1][tid] = acc1;
  __syncthreads();
  const float* wp = wpT + tid;
  float a0 = 0.0f, a1 = 0.0f, c0 = 0.0f, c1 = 0.0f;
  #pragma unroll 8
  for (int c = 0; c < CC; c += 2) {
    float w0 = wp[(c + 0) * CC];
    float w1 = wp[(c + 1) * CC];
    a0 += yv[0][c] * w0;  a1 += yv[0][c + 1] * w1;
    c0 += yv[1][c] * w0;  c1 += yv[1][c + 1] * w1;
  }
  float bp = b_proj[tid];
  out[((size_t)(b * NWIN + np0)) * CC + tid]     = bp + (a0 + a1);
  out[((size_t)(b * NWIN + np0 + 1)) * CC + tid] = bp + (c0 + c1);
}

extern "C" void kernel_launch(void* const* d_in, const int* in_sizes, int n_in,
                              void* d_out, int out_size, void* d_ws, size_t ws_size,
                              hipStream_t stream) {
  const float* x        = (const float*)d_in[0];
  const float* polys    = (const float*)d_in[1];
  const float* w_qkv    = (const float*)d_in[2];
  const float* b_qkv    = (const float*)d_in[3];
  const float* w_proj   = (const float*)d_in[4];
  const float* b_proj   = (const float*)d_in[5];
  const float* conv_w   = (const float*)d_in[6];
  const float* conv_b   = (const float*)d_in[7];
  float* out = (float*)d_out;

  char* ws = (char*)d_ws;
  float* xT = (float*)ws;
  unsigned short* wbp = (unsigned short*)(ws + XT_BYTES);
  float* wpT = (float*)(ws + XT_BYTES + WB_BYTES);
  unsigned short* o16 = (unsigned short*)(ws + XT_BYTES + WB_BYTES + WPT_BYTES);

  hipLaunchKernelGGL(k0_prep, dim3(673), dim3(256), 0, stream, x, xT, w_qkv, wbp, w_proj, wpT);
  hipLaunchKernelGGL(k12_fused, dim3(NWIN, B_), dim3(256), 0, stream,
                     xT, polys, wbp, b_qkv, o16);
  hipLaunchKernelGGL(k3_conv_proj, dim3(300, B_), dim3(256), 0, stream,
                     o16, conv_w, conv_b, wpT, b_proj, out);
}